// Round 4
// baseline (314.777 us; speedup 1.0000x reference)
//
#include <hip/hip_runtime.h>
#include <hip/hip_cooperative_groups.h>

// KNN argmin over L2, round 23: single cooperative kernel (prep + phaseA +
// phaseB fused with 2 grid.sync()s).
//
// R22 post-mortem: sched_barrier fence was a codegen no-op (VGPR 56->56,
// dur 49.2->49.4). phaseB sits at 13% HBM / 28% VALU / 0 MFMA / 33% occ --
// NO pipe near a ceiling. Meanwhile the dark side: phaseA work is ~2.1e6
// MFMAs ~= 7-12us and prep ~16MB ~= 3-8us, yet prep+phaseA ~= 96us by
// subtraction, with BOTH always < 48.8 (never in top-5). Only consistent
// reading: ~45us per-DISPATCH fixed cost dominates all three kernels.
// That retro-explains the entire R15-R22 plateau: intra-kernel opts were
// shaving a small work term riding on a fixed floor.
//
// R23: one persistent cooperative kernel, grid sized via
// hipOccupancyMaxActiveBlocksPerMultiprocessor (co-residency guaranteed),
// phases separated by cooperative_groups grid sync. Bodies are the R22
// ones verbatim (bitwise-identical math; absmax must stay 0). Fallback to
// the 3-dispatch R22 path if cooperative launch errors.
//
// Certified filter unchanged: c = 2^-9*1.01 <= 0.002, eps = 0.004*|q|^2
// + 0.05; bmin encodes key_L(s) = 0.998|s|^2 - 2*cross_a. Rescoring all
// blocks with bmin <= min + eps provably contains the true first argmin.
//
// Ledger: R19 153.3 (phaseB 55.8). R20 steal: 153.0 (phaseB 54.3, occ
// 27->45, time flat). R21 reg-staging: 145.8 (phaseB 49.2). R22 fence:
// 148.3 (no-op; VGPR pinned 56). Fixed-floor theory => fusion is the
// decisive experiment: predict 60-85us if right, ~140 if wrong.

#define NTOT   16384
#define DIM    64
#define EPS_COEF 0.004f   // 2c with c=0.002 (>= 2^-9*1.01)
#define EPS_ABS  0.05f
#define CINIT_COEF (-0.499f)  // -(1-c)/2
#define FLT_BIG 3.4e38f

namespace cg = cooperative_groups;

typedef __attribute__((ext_vector_type(8))) short short8;
typedef __attribute__((ext_vector_type(4))) float float4v;

__device__ __forceinline__ ushort f16_bits(float x) {
  union { _Float16 f; ushort u; } c;
  c.f = (_Float16)x;  // v_cvt_f16_f32, RNE
  return c.u;
}

// Opaque def: forbids rematerialization (forces register residency).
__device__ __forceinline__ void pin8(short8& v) {
  asm volatile("" : "+v"(v));
}

// ---------------------------------------------------------------------------
// Prep body: u in [0,512). u<256 -> S side (f16 panels + sqS + sqSc + S_T);
// u>=256 -> Q side (f16 panels + sqQ). Panel layout (R8-proven):
//   off(r,k) = (r>>4)*1024 + (k>>5)*512 + (((k&31)>>3)*16 + (r&15))*8 + (k&7)
__device__ __forceinline__ void prep_body(
    int u, const float* __restrict__ S, const float* __restrict__ Q,
    ushort* __restrict__ Sh, ushort* __restrict__ Qh,
    float* __restrict__ sqS, float* __restrict__ sqQ,
    float* __restrict__ sqSc, float* __restrict__ S_T,
    float (*tile)[65]) {
  const int tid = threadIdx.x;
  const bool isS = u < 256;
  const int rbase = (u & 255) * 64;
  const float* __restrict__ src = isS ? S : Q;
  ushort* __restrict__ dh = isS ? Sh : Qh;

  const int tx = tid & 63;
  const int ty = tid >> 6;
#pragma unroll
  for (int i = 0; i < 16; ++i) {
    const int r = i * 4 + ty;
    tile[r][tx] = src[(size_t)(rbase + r) * DIM + tx];  // coalesced
  }
  __syncthreads();

  if (isS) {  // transposed copy (coalesced, pad-safe)
#pragma unroll
    for (int i = 0; i < 16; ++i) {
      const int d = i * 4 + ty;
      S_T[(size_t)d * NTOT + rbase + tx] = tile[tx][d];
    }
  }

  // Panel-swizzled f16; stores are lane-contiguous 16B.
  const int panel = tid >> 6;           // 0..3
  const int half = (tid >> 5) & 1;      // k-half
  const int slot0 = (tid & 31) * 2;     // slot = q8*16 + m
#pragma unroll
  for (int ss = 0; ss < 2; ++ss) {
    const int s = slot0 + ss;
    const int m = s & 15;
    const int q8 = s >> 4;
    const int row = panel * 16 + m;
    const int kb = half * 32 + q8 * 8;
    short8 hv;
#pragma unroll
    for (int j = 0; j < 8; ++j) hv[j] = (short)f16_bits(tile[row][kb + j]);
    const size_t goff =
        (size_t)((rbase >> 4) + panel) * 1024 + (size_t)half * 512 + (size_t)s * 8;
    *(short8*)&dh[goff] = hv;
  }

  // Row sum of squares (+ pre-scaled C-init for phaseA on the S side).
  if (tid < 64) {
    float acc = 0.0f;
#pragma unroll
    for (int d = 0; d < DIM; ++d) {
      const float v = tile[tid][d];
      acc = fmaf(v, v, acc);
    }
    if (isS) {
      sqS[rbase + tid] = acc;
      sqSc[rbase + tid] = CINIT_COEF * acc;  // same v_mul RNE as before
    } else {
      sqQ[rbase + tid] = acc;
    }
  }
  __syncthreads();  // tile reuse safety for the persistent loop
}

// ---------------------------------------------------------------------------
// Phase A body: (split, qbase) unit = 4 waves x (64 queries x 2048 supports)
// 16x16x32 f16 MFMA (R4-R18 HW-verified fragment family). C init from sqSc
// (bitwise-identical to in-kernel mul); 2-MFMA chain; v_max3-shaped fold.

#define MFMA16F(A, B, C) __builtin_amdgcn_mfma_f32_16x16x32_f16(A, B, C, 0, 0, 0)

#define STEP_COMPUTE(H0, H1, SQ)                                           \
  do {                                                                     \
    float4v cinit;                                                         \
    cinit[0] = SQ.x;                                                       \
    cinit[1] = SQ.y;                                                       \
    cinit[2] = SQ.z;                                                       \
    cinit[3] = SQ.w;                                                       \
    _Pragma("unroll")                                                      \
    for (int t = 0; t < 4; ++t) {                                          \
      float4v a = MFMA16F(H0, qh[t][0], cinit);                            \
      a = MFMA16F(H1, qh[t][1], a);                                        \
      /* 2x v_max3: max3(a0,a1,a2), then max3(., a3, bmr). Exact. */       \
      bmr[t] = fmaxf(fmaxf(fmaxf(a[0], a[1]), a[2]), fmaxf(a[3], bmr[t])); \
    }                                                                      \
  } while (0)

template <int BST>  // steps per bmin block (8 -> 128-support granularity)
__device__ __forceinline__ void phaseA_body(
    int split, int qbase,
    const ushort* __restrict__ Sh, const ushort* __restrict__ Qh,
    const float* __restrict__ sqSc, float* __restrict__ bmin) {
  constexpr int NSB = NTOT / (16 * BST);
  const int tid = threadIdx.x;
  const int l = tid & 63;
  const int w = tid >> 6;
  const int lm = l & 15;
  const int lq = l >> 4;
  const int sbase = split * 2048 + w * 512;

  // Query (B) fragments: 4 tiles x 2 k-chunks, pinned (resident).
  short8 qh[4][2];
#pragma unroll
  for (int t = 0; t < 4; ++t) {
    const size_t pb = (size_t)((qbase >> 4) + t) * 1024 + (size_t)l * 8;
    qh[t][0] = *(const short8*)&Qh[pb];
    qh[t][1] = *(const short8*)&Qh[pb + 512];
  }
#pragma unroll
  for (int t = 0; t < 4; ++t) {
    pin8(qh[t][0]);
    pin8(qh[t][1]);
  }

  const ushort* pSh = Sh + (size_t)(sbase >> 4) * 1024 + (size_t)l * 8;
  const float* psq = sqSc + sbase + lq * 4;

  // Copy-free double buffer: even steps use (a), odd steps use (b).
  short8 h0a = *(const short8*)(pSh);
  short8 h1a = *(const short8*)(pSh + 512);
  float4 sqa = *(const float4*)(psq);
  short8 h0b = *(const short8*)(pSh + 1024);
  short8 h1b = *(const short8*)(pSh + 1024 + 512);
  float4 sqb = *(const float4*)(psq + 16);

  float bmr[4] = {-FLT_BIG, -FLT_BIG, -FLT_BIG, -FLT_BIG};

  for (int st = 0; st < 32; st += 2) {
    STEP_COMPUTE(h0a, h1a, sqa);
    if (st + 2 < 32) {
      const int off = (st + 2) * 1024;
      h0a = *(const short8*)(pSh + off);
      h1a = *(const short8*)(pSh + off + 512);
      sqa = *(const float4*)(psq + (st + 2) * 16);
    }
    STEP_COMPUTE(h0b, h1b, sqb);
    if (st + 3 < 32) {
      const int off = (st + 3) * 1024;
      h0b = *(const short8*)(pSh + off);
      h1b = *(const short8*)(pSh + off + 512);
      sqb = *(const float4*)(psq + (st + 3) * 16);
    }
    if (((st + 1) & (BST - 1)) == (BST - 1)) {  // finished a bmin block
      const int gb = split * (128 / BST) + w * (32 / BST) + ((st + 1) / BST);
#pragma unroll
      for (int t = 0; t < 4; ++t) {
        float v = bmr[t];
        v = fmaxf(v, __shfl_xor(v, 16, 64));
        v = fmaxf(v, __shfl_xor(v, 32, 64));
        if (lq == 0) bmin[(size_t)(qbase + t * 16 + lm) * NSB + gb] = -2.0f * v;
        bmr[t] = -FLT_BIG;
      }
    }
  }
}

// ---------------------------------------------------------------------------
// Phase B body: unit = 4 queries (one per wave), within-block work stealing
// + register-staged rescore. Exact fp32 keys, row-ascending accumulation;
// strict-< ascending per lane + lexicographic merges => first-index.
template <int SBLK>
struct BShare {
  static constexpr int NB64 = (NTOT / SBLK) / 64;
  float sQrow[4][64];
  unsigned long long smask[4][NB64];
  float sbk[4][4];
  int sbi[4][4];
};

template <int SBLK>
__device__ __forceinline__ void phaseB_body(
    int ublk, const float* __restrict__ S_T, const float* __restrict__ Q,
    const float* __restrict__ sqS, const float* __restrict__ sqQ,
    const float* __restrict__ bmin, const float* __restrict__ onehot,
    float* __restrict__ out, BShare<SBLK>& sh) {
  constexpr int NSB = NTOT / SBLK;    // 128 or 64
  constexpr int NB64 = NSB / 64;
  constexpr int SPL = SBLK / 64;      // supports per lane: 2 or 4

  const int lane = threadIdx.x & 63;
  const int w = threadIdx.x >> 6;
  const int q = ublk * 4 + w;

  __syncthreads();  // LDS reuse safety across persistent-loop iterations

  if (lane < 16)
    *(float4*)&sh.sQrow[w][lane * 4] = *(const float4*)&Q[(size_t)q * DIM + lane * 4];

  // Per-query certified filter width (no global data needed).
  const float eps = EPS_COEF * sqQ[q] + EPS_ABS;

  float bv[NB64];
#pragma unroll
  for (int j = 0; j < NB64; ++j) bv[j] = bmin[(size_t)q * NSB + j * 64 + lane];
  float m = bv[0];
#pragma unroll
  for (int j = 1; j < NB64; ++j) m = fminf(m, bv[j]);
#pragma unroll
  for (int d = 1; d < 64; d <<= 1) m = fminf(m, __shfl_xor(m, d, 64));
  const float thr = m + eps;

#pragma unroll
  for (int j = 0; j < NB64; ++j) {
    const unsigned long long msk = __ballot(bv[j] <= thr);
    if (lane == 0) sh.smask[w][j] = msk;
  }
  __syncthreads();  // sQrow + smask visible block-wide

  // Round-robin the combined worklist. Items of a given query are visited
  // in ascending block order by every wave => per-lane ascending support
  // index => strict-< keeps the FIRST minimum.
  int idx = 0;
  for (int qq = 0; qq < 4; ++qq) {
    float bkq = FLT_BIG;
    int biq = 0;
    for (int j = 0; j < NB64; ++j) {
      unsigned long long msk = sh.smask[qq][j];  // uniform broadcast read
      while (msk) {  // wave-uniform control
        const int b = j * 64 + (__ffsll((long long)msk) - 1);
        msk &= msk - 1;
        if ((idx++ & 3) != w) continue;
        const int s0 = b * SBLK + lane * SPL;
        if (SPL == 2) {
          // Register-staged: 2 halves x {32 float2 loads -> 64 fmaf}.
          float a0 = 0.f, a1 = 0.f;
#pragma unroll
          for (int h = 0; h < 2; ++h) {
            float2 x[32];
#pragma unroll
            for (int d = 0; d < 32; ++d)
              x[d] = *(const float2*)&S_T[(size_t)(h * 32 + d) * NTOT + s0];
#pragma unroll
            for (int d = 0; d < 32; ++d) {
              const float qd = sh.sQrow[qq][h * 32 + d];
              a0 = fmaf(qd, x[d].x, a0);
              a1 = fmaf(qd, x[d].y, a1);
            }
          }
          const float2 sq2 = *(const float2*)&sqS[s0];
          const float k0 = fmaf(-2.f, a0, sq2.x);
          const float k1 = fmaf(-2.f, a1, sq2.y);
          bool u;  // ascending index, strict < => first minimum per lane
          u = k0 < bkq; bkq = u ? k0 : bkq; biq = u ? s0 : biq;
          u = k1 < bkq; bkq = u ? k1 : bkq; biq = u ? (s0 + 1) : biq;
        } else {
          // Register-staged: 4 quarters x {16 float4 loads -> 64 fmaf}.
          float a0 = 0.f, a1 = 0.f, a2 = 0.f, a3 = 0.f;
#pragma unroll
          for (int hh = 0; hh < 4; ++hh) {
            float4 x[16];
#pragma unroll
            for (int d = 0; d < 16; ++d)
              x[d] = *(const float4*)&S_T[(size_t)(hh * 16 + d) * NTOT + s0];
#pragma unroll
            for (int d = 0; d < 16; ++d) {
              const float qd = sh.sQrow[qq][hh * 16 + d];
              a0 = fmaf(qd, x[d].x, a0);
              a1 = fmaf(qd, x[d].y, a1);
              a2 = fmaf(qd, x[d].z, a2);
              a3 = fmaf(qd, x[d].w, a3);
            }
          }
          const float4 sq4 = *(const float4*)&sqS[s0];
          const float k0 = fmaf(-2.f, a0, sq4.x);
          const float k1 = fmaf(-2.f, a1, sq4.y);
          const float k2 = fmaf(-2.f, a2, sq4.z);
          const float k3 = fmaf(-2.f, a3, sq4.w);
          bool u;
          u = k0 < bkq; bkq = u ? k0 : bkq; biq = u ? s0 : biq;
          u = k1 < bkq; bkq = u ? k1 : bkq; biq = u ? (s0 + 1) : biq;
          u = k2 < bkq; bkq = u ? k2 : bkq; biq = u ? (s0 + 2) : biq;
          u = k3 < bkq; bkq = u ? k3 : bkq; biq = u ? (s0 + 3) : biq;
        }
      }
    }
    // Cross-lane lexicographic argmin on exact keys => first-index.
#pragma unroll
    for (int d = 1; d < 64; d <<= 1) {
      const float ok = __shfl_xor(bkq, d, 64);
      const int oi = __shfl_xor(biq, d, 64);
      const bool u = (ok < bkq) || (ok == bkq && oi < biq);
      bkq = u ? ok : bkq;
      biq = u ? oi : biq;
    }
    if (lane == 0) { sh.sbk[qq][w] = bkq; sh.sbi[qq][w] = biq; }
  }
  __syncthreads();

  // Wave w: lexicographic merge of the 4 wave partials for query w.
  float fk = sh.sbk[w][0];
  int fi = sh.sbi[w][0];
#pragma unroll
  for (int ww = 1; ww < 4; ++ww) {
    const float ok = sh.sbk[w][ww];
    const int oi = sh.sbi[w][ww];
    const bool u = (ok < fk) || (ok == fk && oi < fi);
    fk = u ? ok : fk;
    fi = u ? oi : fi;
  }

  // Label: one-hot rows exact {0,1}; first 1 == np.argmax.
  const float ov = onehot[(size_t)fi * 64 + lane];
  const unsigned long long lmask = __ballot(ov > 0.5f);
  const int label = __ffsll((long long)lmask) - 1;
  out[(size_t)q * 64 + lane] = (lane == label) ? 1.0f : 0.0f;
}

// ---------------------------------------------------------------------------
// Fused persistent cooperative kernel: prep -> grid.sync -> phaseA ->
// grid.sync -> phaseB. LDS is a union of prep's tile and phaseB's share.
template <int BST>
__global__ __launch_bounds__(256, 3) void k_fused(
    const float* __restrict__ S, const float* __restrict__ Q,
    const float* __restrict__ OH, float* __restrict__ out,
    ushort* __restrict__ Sh, ushort* __restrict__ Qh,
    float* __restrict__ sqS, float* __restrict__ sqQ,
    float* __restrict__ sqSc, float* __restrict__ S_T,
    float* __restrict__ bmin) {
  constexpr int SBLK = 16 * BST;
  __shared__ __align__(16) char smraw[sizeof(float) * 64 * 65];
  static_assert(sizeof(BShare<SBLK>) <= sizeof(float) * 64 * 65, "lds");
  float (*tile)[65] = reinterpret_cast<float(*)[65]>(smraw);
  BShare<SBLK>* bs = reinterpret_cast<BShare<SBLK>*>(smraw);

  const int G = gridDim.x;
  for (int u = blockIdx.x; u < 512; u += G)
    prep_body(u, S, Q, Sh, Qh, sqS, sqQ, sqSc, S_T, tile);
  cg::this_grid().sync();
  for (int u = blockIdx.x; u < 2048; u += G)
    phaseA_body<BST>(u & 7, (u >> 3) * 64, Sh, Qh, sqSc, bmin);
  cg::this_grid().sync();
  for (int u = blockIdx.x; u < NTOT / 4; u += G)
    phaseB_body<SBLK>(u, S_T, Q, sqS, sqQ, bmin, OH, out, *bs);
}

// ---------------------------------------------------------------------------
// Standalone fallback kernels (R22 path) in case cooperative launch errors.
__global__ __launch_bounds__(256) void k_prep(
    const float* __restrict__ S, const float* __restrict__ Q,
    ushort* __restrict__ Sh, ushort* __restrict__ Qh,
    float* __restrict__ sqS, float* __restrict__ sqQ,
    float* __restrict__ sqSc, float* __restrict__ S_T) {
  __shared__ float tile[64][65];
  prep_body(blockIdx.x, S, Q, Sh, Qh, sqS, sqQ, sqSc, S_T, tile);
}

template <int BST>
__global__ __launch_bounds__(256, 3) void k_phaseA(
    const ushort* __restrict__ Sh, const ushort* __restrict__ Qh,
    const float* __restrict__ sqSc, float* __restrict__ bmin) {
  phaseA_body<BST>(blockIdx.x, blockIdx.y * 64, Sh, Qh, sqSc, bmin);
}

template <int SBLK>
__global__ __launch_bounds__(256, 3) void k_phaseB(
    const float* __restrict__ S_T, const float* __restrict__ Q,
    const float* __restrict__ sqS, const float* __restrict__ sqQ,
    const float* __restrict__ bmin, const float* __restrict__ onehot,
    float* __restrict__ out) {
  __shared__ BShare<SBLK> sh;
  phaseB_body<SBLK>(blockIdx.x, S_T, Q, sqS, sqQ, bmin, onehot, out, sh);
}

// ---------------------------------------------------------------------------
extern "C" void kernel_launch(void* const* d_in, const int* in_sizes, int n_in,
                              void* d_out, int out_size, void* d_ws, size_t ws_size,
                              hipStream_t stream) {
  const float* S = (const float*)d_in[0];   // [16384][64]
  const float* Q = (const float*)d_in[1];   // [16384][64]
  const float* OH = (const float*)d_in[2];  // [16384][64]
  float* out = (float*)d_out;

  char* ws = (char*)d_ws;
  ushort* Sh = (ushort*)ws;                                  // [0, 2MB)
  ushort* Qh = (ushort*)(ws + (2u << 20));                   // [2, 4MB)
  float* S_T = (float*)(ws + (4u << 20));                    // [4, 8MB)
  float* sqS = (float*)(ws + (8u << 20));                    // 64 KB
  float* sqQ = (float*)(ws + (8u << 20) + (64u << 10));      // 64 KB
  float* sqSc = (float*)(ws + (8u << 20) + (128u << 10));    // 64 KB
  float* bmin = (float*)(ws + (8u << 20) + (192u << 10));    // up to 8 MB

  const bool big = ws_size >= (17u << 20);

  // Cooperative fused path: grid sized to guaranteed co-residency.
  int nb = 0;
  hipError_t oe;
  if (big)
    oe = hipOccupancyMaxActiveBlocksPerMultiprocessor(&nb, k_fused<8>, 256, 0);
  else
    oe = hipOccupancyMaxActiveBlocksPerMultiprocessor(&nb, k_fused<16>, 256, 0);
  bool done = false;
  if (oe == hipSuccess && nb >= 1) {
    int G = nb * 256;  // 256 CUs on MI355X
    if (G > 2048) G = 2048;
    void* args[] = {(void*)&S, (void*)&Q, (void*)&OH, (void*)&out,
                    (void*)&Sh, (void*)&Qh, (void*)&sqS, (void*)&sqQ,
                    (void*)&sqSc, (void*)&S_T, (void*)&bmin};
    hipError_t le;
    if (big)
      le = hipLaunchCooperativeKernel(k_fused<8>, dim3(G), dim3(256), args, 0,
                                      stream);
    else
      le = hipLaunchCooperativeKernel(k_fused<16>, dim3(G), dim3(256), args, 0,
                                      stream);
    done = (le == hipSuccess);
    if (!done) (void)hipGetLastError();  // clear sticky error, fall back
  }

  if (!done) {  // R22 3-dispatch fallback
    k_prep<<<dim3(512), 256, 0, stream>>>(S, Q, Sh, Qh, sqS, sqQ, sqSc, S_T);
    if (big) {
      k_phaseA<8><<<dim3(8, NTOT / 64), 256, 0, stream>>>(Sh, Qh, sqSc, bmin);
      k_phaseB<128><<<dim3(NTOT / 4), 256, 0, stream>>>(S_T, Q, sqS, sqQ,
                                                        bmin, OH, out);
    } else {
      k_phaseA<16><<<dim3(8, NTOT / 64), 256, 0, stream>>>(Sh, Qh, sqSc, bmin);
      k_phaseB<256><<<dim3(NTOT / 4), 256, 0, stream>>>(S_T, Q, sqS, sqQ,
                                                        bmin, OH, out);
    }
  }
  (void)in_sizes; (void)n_in; (void)out_size; (void)ws_size;
}

// Round 5
// 153.102 us; speedup vs baseline: 2.0560x; 2.0560x over previous
//
#include <hip/hip_runtime.h>

// KNN argmin over L2, round 24: revert fusion; phaseA 128-query tiles.
//
// R23 post-mortem: fused cooperative kernel = 357us/dispatch with
// WRITE_SIZE 38MB (vs 4MB output) and VGPR 64 -> merged regalloc spilled
// phaseB staging + phaseA frags to scratch. Fusion dead; not a clean test
// of dispatch overhead.
//
// Revised dark-96us theory: phaseA re-reads the Sh panel once per q-tile:
// 256 tiles x 16384 supports x 128B ~= 770MB (incl sqSc) from L2/L3
// (~22us floor) AND its inner loop is VALU-issue-bound (52 VALU cy vs
// 38 MFMA cy per 16-support step). Both scale as NQ/QTILE. R24 widens the
// q-tile 64 -> 128: traffic halves, and per-step balance becomes ~76 VALU
// vs ~77 MFMA cy. qh[8][2] pinned = 64 VGPR, total ~120 < 170 cap of
// launch_bounds(256,3) -> no spill. Grid 8x128 = 4 blocks/CU exactly;
// blockIdx.x=split keeps each split's 256KB Sh slice XCD-local.
//
// phaseB: R21 body verbatim (best measured, 49.2us; R22 fences were
// codegen no-ops, removed). prep: R22 body (sqSc precompute kept).
//
// Certified filter unchanged: c = 2^-9*1.01 <= 0.002, eps = 0.004*|q|^2
// + 0.05; bmin encodes key_L(s) = 0.998|s|^2 - 2*cross_a via cinit
// = -0.499*|s|^2 folded into phaseA's C-init. Rescoring all blocks with
// bmin <= min + eps provably contains the true first argmin.
//
// Ledger: R19 153.3 (phaseB 55.8) | R20 steal 153.0 (phaseB 54.3, occ
// 27->45, flat => latency-chain) | R21 reg-staging 145.8 (phaseB 49.2) |
// R22 fence no-op 148.3 | R23 fusion 314.8 (spill catastrophe, reverted).

#define NTOT   16384
#define DIM    64
#define EPS_COEF 0.004f   // 2c with c=0.002 (>= 2^-9*1.01)
#define EPS_ABS  0.05f
#define CINIT_COEF (-0.499f)  // -(1-c)/2
#define FLT_BIG 3.4e38f

typedef __attribute__((ext_vector_type(8))) short short8;
typedef __attribute__((ext_vector_type(4))) float float4v;

__device__ __forceinline__ ushort f16_bits(float x) {
  union { _Float16 f; ushort u; } c;
  c.f = (_Float16)x;  // v_cvt_f16_f32, RNE
  return c.u;
}

// Opaque def: forbids rematerialization (forces register residency).
__device__ __forceinline__ void pin8(short8& v) {
  asm volatile("" : "+v"(v));
}

// ---------------------------------------------------------------------------
// Fused prep: blocks 0..255 -> S (f16 panels + sqS + sqSc + S_T);
// blocks 256..511 -> Q (f16 panels + sqQ). Panel layout (R8-proven):
//   off(r,k) = (r>>4)*1024 + (k>>5)*512 + (((k&31)>>3)*16 + (r&15))*8 + (k&7)
__global__ __launch_bounds__(256) void k_prep(
    const float* __restrict__ S, const float* __restrict__ Q,
    ushort* __restrict__ Sh, ushort* __restrict__ Qh,
    float* __restrict__ sqS, float* __restrict__ sqQ,
    float* __restrict__ sqSc, float* __restrict__ S_T) {
  __shared__ float tile[64][65];
  const int tid = threadIdx.x;
  const bool isS = blockIdx.x < 256;
  const int rbase = (blockIdx.x & 255) * 64;
  const float* __restrict__ src = isS ? S : Q;
  ushort* __restrict__ dh = isS ? Sh : Qh;

  const int tx = tid & 63;
  const int ty = tid >> 6;
#pragma unroll
  for (int i = 0; i < 16; ++i) {
    const int r = i * 4 + ty;
    tile[r][tx] = src[(size_t)(rbase + r) * DIM + tx];  // coalesced
  }
  __syncthreads();

  if (isS) {  // transposed copy (coalesced, pad-safe)
#pragma unroll
    for (int i = 0; i < 16; ++i) {
      const int d = i * 4 + ty;
      S_T[(size_t)d * NTOT + rbase + tx] = tile[tx][d];
    }
  }

  // Panel-swizzled f16; stores are lane-contiguous 16B.
  const int panel = tid >> 6;           // 0..3
  const int half = (tid >> 5) & 1;      // k-half
  const int slot0 = (tid & 31) * 2;     // slot = q8*16 + m
#pragma unroll
  for (int ss = 0; ss < 2; ++ss) {
    const int s = slot0 + ss;
    const int m = s & 15;
    const int q8 = s >> 4;
    const int row = panel * 16 + m;
    const int kb = half * 32 + q8 * 8;
    short8 hv;
#pragma unroll
    for (int j = 0; j < 8; ++j) hv[j] = (short)f16_bits(tile[row][kb + j]);
    const size_t goff =
        (size_t)((rbase >> 4) + panel) * 1024 + (size_t)half * 512 + (size_t)s * 8;
    *(short8*)&dh[goff] = hv;
  }

  // Row sum of squares (+ pre-scaled C-init for phaseA on the S side).
  if (tid < 64) {
    float acc = 0.0f;
#pragma unroll
    for (int d = 0; d < DIM; ++d) {
      const float v = tile[tid][d];
      acc = fmaf(v, v, acc);
    }
    if (isS) {
      sqS[rbase + tid] = acc;
      sqSc[rbase + tid] = CINIT_COEF * acc;  // same v_mul RNE as before
    } else {
      sqQ[rbase + tid] = acc;
    }
  }
}

// ---------------------------------------------------------------------------
// Phase A (R24): block = 4 waves; wave w: 128 queries x 512 supports.
// grid = (8 splits, 128 q-tiles). 16x16x32 f16 MFMA (R4-R18 HW-verified
// fragment family). C init from sqSc (bitwise-identical); one cinit per
// step shared as C operand by all 8 tiles; 2-MFMA chain per tile;
// v_max3-shaped block-max fold => bmin = -2*max = blockmin key_L.

#define MFMA16F(A, B, C) __builtin_amdgcn_mfma_f32_16x16x32_f16(A, B, C, 0, 0, 0)

#define STEP_COMPUTE(H0, H1, SQ)                                           \
  do {                                                                     \
    float4v cinit;                                                         \
    cinit[0] = SQ.x;                                                       \
    cinit[1] = SQ.y;                                                       \
    cinit[2] = SQ.z;                                                       \
    cinit[3] = SQ.w;                                                       \
    _Pragma("unroll")                                                      \
    for (int t = 0; t < 8; ++t) {                                          \
      float4v a = MFMA16F(H0, qh[t][0], cinit);                            \
      a = MFMA16F(H1, qh[t][1], a);                                        \
      /* v_max3(a0,a1,a2), v_max(a3,bmr), v_max. Exact (assoc). */         \
      bmr[t] = fmaxf(fmaxf(fmaxf(a[0], a[1]), a[2]), fmaxf(a[3], bmr[t])); \
    }                                                                      \
  } while (0)

template <int BST>  // steps per bmin block (8 -> 128-support granularity)
__global__ __launch_bounds__(256, 3) void k_phaseA(
    const ushort* __restrict__ Sh, const ushort* __restrict__ Qh,
    const float* __restrict__ sqSc, float* __restrict__ bmin) {
  constexpr int NSB = NTOT / (16 * BST);
  const int tid = threadIdx.x;
  const int l = tid & 63;
  const int w = tid >> 6;
  const int lm = l & 15;
  const int lq = l >> 4;
  const int split = blockIdx.x;       // 0..7 (maps 1:1 onto XCDs)
  const int qbase = blockIdx.y * 128;
  const int sbase = split * 2048 + w * 512;

  // Query (B) fragments: 8 tiles x 2 k-chunks, pinned (64 VGPR resident).
  short8 qh[8][2];
#pragma unroll
  for (int t = 0; t < 8; ++t) {
    const size_t pb = (size_t)((qbase >> 4) + t) * 1024 + (size_t)l * 8;
    qh[t][0] = *(const short8*)&Qh[pb];
    qh[t][1] = *(const short8*)&Qh[pb + 512];
  }
#pragma unroll
  for (int t = 0; t < 8; ++t) {
    pin8(qh[t][0]);
    pin8(qh[t][1]);
  }

  const ushort* pSh = Sh + (size_t)(sbase >> 4) * 1024 + (size_t)l * 8;
  const float* psq = sqSc + sbase + lq * 4;

  // Copy-free double buffer: even steps use (a), odd steps use (b).
  short8 h0a = *(const short8*)(pSh);
  short8 h1a = *(const short8*)(pSh + 512);
  float4 sqa = *(const float4*)(psq);
  short8 h0b = *(const short8*)(pSh + 1024);
  short8 h1b = *(const short8*)(pSh + 1024 + 512);
  float4 sqb = *(const float4*)(psq + 16);

  float bmr[8];
#pragma unroll
  for (int t = 0; t < 8; ++t) bmr[t] = -FLT_BIG;

  for (int st = 0; st < 32; st += 2) {
    STEP_COMPUTE(h0a, h1a, sqa);
    if (st + 2 < 32) {
      const int off = (st + 2) * 1024;
      h0a = *(const short8*)(pSh + off);
      h1a = *(const short8*)(pSh + off + 512);
      sqa = *(const float4*)(psq + (st + 2) * 16);
    }
    STEP_COMPUTE(h0b, h1b, sqb);
    if (st + 3 < 32) {
      const int off = (st + 3) * 1024;
      h0b = *(const short8*)(pSh + off);
      h1b = *(const short8*)(pSh + off + 512);
      sqb = *(const float4*)(psq + (st + 3) * 16);
    }
    if (((st + 1) & (BST - 1)) == (BST - 1)) {  // finished a bmin block
      const int gb = split * (128 / BST) + w * (32 / BST) + ((st + 1) / BST);
#pragma unroll
      for (int t = 0; t < 8; ++t) {
        float v = bmr[t];
        v = fmaxf(v, __shfl_xor(v, 16, 64));
        v = fmaxf(v, __shfl_xor(v, 32, 64));
        if (lq == 0) bmin[(size_t)(qbase + t * 16 + lm) * NSB + gb] = -2.0f * v;
        bmr[t] = -FLT_BIG;
      }
    }
  }
}

// ---------------------------------------------------------------------------
// Phase B (R21 verbatim, best measured): 4 queries per block, within-block
// work stealing + register-staged rescore. launch_bounds(256,3).
// Exact fp32 keys, row-ascending accumulation; strict-< ascending per lane
// + lexicographic merges => first-index.
template <int SBLK>
__global__ __launch_bounds__(256, 3) void k_phaseB(
    const float* __restrict__ S_T,   // [64][NTOT]
    const float* __restrict__ Q,     // [NTOT][64]
    const float* __restrict__ sqS, const float* __restrict__ sqQ,
    const float* __restrict__ bmin,
    const float* __restrict__ onehot, float* __restrict__ out) {
  constexpr int NSB = NTOT / SBLK;    // 128 or 64
  constexpr int NB64 = NSB / 64;
  constexpr int SPL = SBLK / 64;      // supports per lane: 2 or 4

  __shared__ float sQrow[4][64];
  __shared__ unsigned long long smask[4][NB64];
  __shared__ float sbk[4][4];
  __shared__ int sbi[4][4];

  const int lane = threadIdx.x & 63;
  const int w = threadIdx.x >> 6;
  const int q = blockIdx.x * 4 + w;

  if (lane < 16)
    *(float4*)&sQrow[w][lane * 4] = *(const float4*)&Q[(size_t)q * DIM + lane * 4];

  // Per-query certified filter width (no global data needed).
  const float eps = EPS_COEF * sqQ[q] + EPS_ABS;

  float bv[NB64];
#pragma unroll
  for (int j = 0; j < NB64; ++j) bv[j] = bmin[(size_t)q * NSB + j * 64 + lane];
  float m = bv[0];
#pragma unroll
  for (int j = 1; j < NB64; ++j) m = fminf(m, bv[j]);
#pragma unroll
  for (int d = 1; d < 64; d <<= 1) m = fminf(m, __shfl_xor(m, d, 64));
  const float thr = m + eps;

#pragma unroll
  for (int j = 0; j < NB64; ++j) {
    const unsigned long long msk = __ballot(bv[j] <= thr);
    if (lane == 0) smask[w][j] = msk;
  }
  __syncthreads();  // sQrow + smask visible block-wide

  // Round-robin the combined worklist. Items of a given query are visited
  // in ascending block order by every wave => per-lane ascending support
  // index => strict-< keeps the FIRST minimum.
  int idx = 0;
  for (int qq = 0; qq < 4; ++qq) {
    float bkq = FLT_BIG;
    int biq = 0;
    for (int j = 0; j < NB64; ++j) {
      unsigned long long msk = smask[qq][j];  // uniform broadcast read
      while (msk) {  // wave-uniform control
        const int b = j * 64 + (__ffsll((long long)msk) - 1);
        msk &= msk - 1;
        if ((idx++ & 3) != w) continue;
        const int s0 = b * SBLK + lane * SPL;
        if (SPL == 2) {
          // Register-staged: 2 halves x {32 float2 loads -> 64 fmaf}.
          float a0 = 0.f, a1 = 0.f;
#pragma unroll
          for (int h = 0; h < 2; ++h) {
            float2 x[32];
#pragma unroll
            for (int d = 0; d < 32; ++d)
              x[d] = *(const float2*)&S_T[(size_t)(h * 32 + d) * NTOT + s0];
#pragma unroll
            for (int d = 0; d < 32; ++d) {
              const float qd = sQrow[qq][h * 32 + d];
              a0 = fmaf(qd, x[d].x, a0);
              a1 = fmaf(qd, x[d].y, a1);
            }
          }
          const float2 sq2 = *(const float2*)&sqS[s0];
          const float k0 = fmaf(-2.f, a0, sq2.x);
          const float k1 = fmaf(-2.f, a1, sq2.y);
          bool u;  // ascending index, strict < => first minimum per lane
          u = k0 < bkq; bkq = u ? k0 : bkq; biq = u ? s0 : biq;
          u = k1 < bkq; bkq = u ? k1 : bkq; biq = u ? (s0 + 1) : biq;
        } else {
          // Register-staged: 4 quarters x {16 float4 loads -> 64 fmaf}.
          float a0 = 0.f, a1 = 0.f, a2 = 0.f, a3 = 0.f;
#pragma unroll
          for (int hh = 0; hh < 4; ++hh) {
            float4 x[16];
#pragma unroll
            for (int d = 0; d < 16; ++d)
              x[d] = *(const float4*)&S_T[(size_t)(hh * 16 + d) * NTOT + s0];
#pragma unroll
            for (int d = 0; d < 16; ++d) {
              const float qd = sQrow[qq][hh * 16 + d];
              a0 = fmaf(qd, x[d].x, a0);
              a1 = fmaf(qd, x[d].y, a1);
              a2 = fmaf(qd, x[d].z, a2);
              a3 = fmaf(qd, x[d].w, a3);
            }
          }
          const float4 sq4 = *(const float4*)&sqS[s0];
          const float k0 = fmaf(-2.f, a0, sq4.x);
          const float k1 = fmaf(-2.f, a1, sq4.y);
          const float k2 = fmaf(-2.f, a2, sq4.z);
          const float k3 = fmaf(-2.f, a3, sq4.w);
          bool u;
          u = k0 < bkq; bkq = u ? k0 : bkq; biq = u ? s0 : biq;
          u = k1 < bkq; bkq = u ? k1 : bkq; biq = u ? (s0 + 1) : biq;
          u = k2 < bkq; bkq = u ? k2 : bkq; biq = u ? (s0 + 2) : biq;
          u = k3 < bkq; bkq = u ? k3 : bkq; biq = u ? (s0 + 3) : biq;
        }
      }
    }
    // Cross-lane lexicographic argmin on exact keys => first-index.
#pragma unroll
    for (int d = 1; d < 64; d <<= 1) {
      const float ok = __shfl_xor(bkq, d, 64);
      const int oi = __shfl_xor(biq, d, 64);
      const bool u = (ok < bkq) || (ok == bkq && oi < biq);
      bkq = u ? ok : bkq;
      biq = u ? oi : biq;
    }
    if (lane == 0) { sbk[qq][w] = bkq; sbi[qq][w] = biq; }
  }
  __syncthreads();

  // Wave w: lexicographic merge of the 4 wave partials for query w.
  // (Disjoint block subsets; ties resolved by smaller index => first-index.)
  float fk = sbk[w][0];
  int fi = sbi[w][0];
#pragma unroll
  for (int ww = 1; ww < 4; ++ww) {
    const float ok = sbk[w][ww];
    const int oi = sbi[w][ww];
    const bool u = (ok < fk) || (ok == fk && oi < fi);
    fk = u ? ok : fk;
    fi = u ? oi : fi;
  }

  // Label: one-hot rows exact {0,1}; first 1 == np.argmax.
  const float ov = onehot[(size_t)fi * 64 + lane];
  const unsigned long long lmask = __ballot(ov > 0.5f);
  const int label = __ffsll((long long)lmask) - 1;
  out[(size_t)q * 64 + lane] = (lane == label) ? 1.0f : 0.0f;
}

// ---------------------------------------------------------------------------
extern "C" void kernel_launch(void* const* d_in, const int* in_sizes, int n_in,
                              void* d_out, int out_size, void* d_ws, size_t ws_size,
                              hipStream_t stream) {
  const float* S = (const float*)d_in[0];   // [16384][64]
  const float* Q = (const float*)d_in[1];   // [16384][64]
  const float* OH = (const float*)d_in[2];  // [16384][64]
  float* out = (float*)d_out;

  char* ws = (char*)d_ws;
  ushort* Sh = (ushort*)ws;                                  // [0, 2MB)
  ushort* Qh = (ushort*)(ws + (2u << 20));                   // [2, 4MB)
  float* S_T = (float*)(ws + (4u << 20));                    // [4, 8MB)
  float* sqS = (float*)(ws + (8u << 20));                    // 64 KB
  float* sqQ = (float*)(ws + (8u << 20) + (64u << 10));      // 64 KB
  float* sqSc = (float*)(ws + (8u << 20) + (128u << 10));    // 64 KB
  float* bmin = (float*)(ws + (8u << 20) + (192u << 10));    // up to 8 MB

  k_prep<<<dim3(512), 256, 0, stream>>>(S, Q, Sh, Qh, sqS, sqQ, sqSc, S_T);

  // 128-granular bmin (8 MB) if workspace allows (proven >=20 MB in R14);
  // else 256-granular (4 MB). Need: 8.19 + 8 = 16.19 MB / 12.19 MB.
  if (ws_size >= (17u << 20)) {
    k_phaseA<8><<<dim3(8, NTOT / 128), 256, 0, stream>>>(Sh, Qh, sqSc, bmin);
    k_phaseB<128><<<dim3(NTOT / 4), 256, 0, stream>>>(S_T, Q, sqS, sqQ,
                                                      bmin, OH, out);
  } else {
    k_phaseA<16><<<dim3(8, NTOT / 128), 256, 0, stream>>>(Sh, Qh, sqSc, bmin);
    k_phaseB<256><<<dim3(NTOT / 4), 256, 0, stream>>>(S_T, Q, sqS, sqQ,
                                                      bmin, OH, out);
  }
  (void)in_sizes; (void)n_in; (void)out_size; (void)ws_size;
}

// Round 6
// 145.790 us; speedup vs baseline: 2.1591x; 1.0502x over previous
//
#include <hip/hip_runtime.h>

// KNN argmin over L2, round 25: LDS-staged phaseA (canonical GEMM shape).
//
// R24 post-mortem: phaseA surfaced at 50.2us with MfmaUtil 27 / VALU 28 /
// HBM 12 / occupancy 22% -- no pipe near ceiling, occupancy halved by the
// 8-tile widening (VGPR 84 + ~64 AGPR > 128 unified threshold -> 8
// waves/CU). Latency-hiding failure: reg-double-buffer prefetch distance
// ~1 double-step vs 200-600cy L2/L3 panel latency. Work floor ~5-10us.
// WRITE_SIZE 36MB = bmin partial-line eviction amplification (HBM 12% =>
// not the pacer; left alone).
//
// R25 phaseA: block = 256 queries x 512 supports; 4 waves SHARE the
// support panel via LDS, double-buffered 64-support chunks staged with
// global_load_lds width=16 (linear dest, lane-contiguous panel layout),
// one barrier per chunk (T3 minimal 2-phase). Support traffic 385->128MB;
// per-wave regs ~80 unified (qh[4][2]=32 pinned) -> 16 waves/CU.
// bmin = max-fold over identical support sets (max exact-commutative) =>
// bitwise-identical output. Grid (32,64): split -> XCD = linear%8 keeps
// each split's 64KB Sh slice XCD-local.
//
// phaseB: R21 body verbatim (best measured 49.2us). prep: unchanged.
//
// Certified filter unchanged: c = 2^-9*1.01 <= 0.002, eps = 0.004*|q|^2
// + 0.05; bmin encodes key_L(s) = 0.998|s|^2 - 2*cross_a via cinit
// = -0.499*|s|^2 (sqSc). Rescoring all blocks with bmin <= min + eps
// provably contains the true first argmin.
//
// Ledger: R19 153.3 | R20 steal 153.0 (occ up, flat) | R21 reg-staging
// 145.8 (phaseB 49.2) | R22 fence no-op 148.3 | R23 fusion 314.8 (spill,
// reverted) | R24 128q phaseA 153.1 (phaseA 50.2 visible: latency-bound,
// occ 22%). Falsifier this round: phaseA >=45us at occ ~45 => uniform
// ~50us/dispatch floor is harness/clock, not kernel-structural.

#define NTOT   16384
#define DIM    64
#define EPS_COEF 0.004f   // 2c with c=0.002 (>= 2^-9*1.01)
#define EPS_ABS  0.05f
#define CINIT_COEF (-0.499f)  // -(1-c)/2
#define FLT_BIG 3.4e38f

typedef __attribute__((ext_vector_type(8))) short short8;
typedef __attribute__((ext_vector_type(4))) float float4v;

__device__ __forceinline__ ushort f16_bits(float x) {
  union { _Float16 f; ushort u; } c;
  c.f = (_Float16)x;  // v_cvt_f16_f32, RNE
  return c.u;
}

// Opaque def: forbids rematerialization (forces register residency).
__device__ __forceinline__ void pin8(short8& v) {
  asm volatile("" : "+v"(v));
}

// ---------------------------------------------------------------------------
// Fused prep: blocks 0..255 -> S (f16 panels + sqS + sqSc + S_T);
// blocks 256..511 -> Q (f16 panels + sqQ). Panel layout (R8-proven):
//   off(r,k) = (r>>4)*1024 + (k>>5)*512 + (((k&31)>>3)*16 + (r&15))*8 + (k&7)
__global__ __launch_bounds__(256) void k_prep(
    const float* __restrict__ S, const float* __restrict__ Q,
    ushort* __restrict__ Sh, ushort* __restrict__ Qh,
    float* __restrict__ sqS, float* __restrict__ sqQ,
    float* __restrict__ sqSc, float* __restrict__ S_T) {
  __shared__ float tile[64][65];
  const int tid = threadIdx.x;
  const bool isS = blockIdx.x < 256;
  const int rbase = (blockIdx.x & 255) * 64;
  const float* __restrict__ src = isS ? S : Q;
  ushort* __restrict__ dh = isS ? Sh : Qh;

  const int tx = tid & 63;
  const int ty = tid >> 6;
#pragma unroll
  for (int i = 0; i < 16; ++i) {
    const int r = i * 4 + ty;
    tile[r][tx] = src[(size_t)(rbase + r) * DIM + tx];  // coalesced
  }
  __syncthreads();

  if (isS) {  // transposed copy (coalesced, pad-safe)
#pragma unroll
    for (int i = 0; i < 16; ++i) {
      const int d = i * 4 + ty;
      S_T[(size_t)d * NTOT + rbase + tx] = tile[tx][d];
    }
  }

  // Panel-swizzled f16; stores are lane-contiguous 16B.
  const int panel = tid >> 6;           // 0..3
  const int half = (tid >> 5) & 1;      // k-half
  const int slot0 = (tid & 31) * 2;     // slot = q8*16 + m
#pragma unroll
  for (int ss = 0; ss < 2; ++ss) {
    const int s = slot0 + ss;
    const int m = s & 15;
    const int q8 = s >> 4;
    const int row = panel * 16 + m;
    const int kb = half * 32 + q8 * 8;
    short8 hv;
#pragma unroll
    for (int j = 0; j < 8; ++j) hv[j] = (short)f16_bits(tile[row][kb + j]);
    const size_t goff =
        (size_t)((rbase >> 4) + panel) * 1024 + (size_t)half * 512 + (size_t)s * 8;
    *(short8*)&dh[goff] = hv;
  }

  // Row sum of squares (+ pre-scaled C-init for phaseA on the S side).
  if (tid < 64) {
    float acc = 0.0f;
#pragma unroll
    for (int d = 0; d < DIM; ++d) {
      const float v = tile[tid][d];
      acc = fmaf(v, v, acc);
    }
    if (isS) {
      sqS[rbase + tid] = acc;
      sqSc[rbase + tid] = CINIT_COEF * acc;  // same v_mul RNE as before
    } else {
      sqQ[rbase + tid] = acc;
    }
  }
}

// ---------------------------------------------------------------------------
// Phase A (R25): block = 256 queries x 512 supports; 4 waves share the
// support panel through LDS. Wave w owns queries qbase+w*64 (qh[4][2]
// pinned). 8 chunks of 64 supports (8KB panel + 256B sqSc), double-
// buffered, staged via global_load_lds (width 16, linear dest), one
// barrier per chunk. 16x16x32 f16 MFMA (R4-R18 HW-verified fragment
// family); C init from sqSc; v_max3-shaped fold; bmin = -2*max.
// grid = (32 splits, 64 q-tiles); split -> XCD via linear%8.

#define MFMA16F(A, B, C) __builtin_amdgcn_mfma_f32_16x16x32_f16(A, B, C, 0, 0, 0)

template <int BST>  // steps(16-support) per bmin block: 8 -> SBLK=128
__global__ __launch_bounds__(256, 4) void k_phaseA(
    const ushort* __restrict__ Sh, const ushort* __restrict__ Qh,
    const float* __restrict__ sqSc, float* __restrict__ bmin) {
  constexpr int NSB = NTOT / (16 * BST);   // 128 or 64
  constexpr int SBLK = 16 * BST;
  __shared__ ushort spanel[2][4096];       // 2 x 8KB: 64 supports each
  __shared__ float ssq[2][64];

  const int tid = threadIdx.x;
  const int l = tid & 63;
  const int w = tid >> 6;
  const int lm = l & 15;
  const int lq = l >> 4;
  const int split = blockIdx.x;            // 0..31
  const int qbase = blockIdx.y * 256 + w * 64;
  const int sbase = split * 512;

  // Query (B) fragments: 4 tiles x 2 k-chunks, pinned (32 VGPR resident).
  short8 qh[4][2];
#pragma unroll
  for (int t = 0; t < 4; ++t) {
    const size_t pb = (size_t)((qbase >> 4) + t) * 1024 + (size_t)l * 8;
    qh[t][0] = *(const short8*)&Qh[pb];
    qh[t][1] = *(const short8*)&Qh[pb + 512];
  }
#pragma unroll
  for (int t = 0; t < 4; ++t) {
    pin8(qh[t][0]);
    pin8(qh[t][1]);
  }

  // Async stage of chunk c into buffer b. Panel layout is lane-contiguous
  // 16B per (panel, l), so the LDS dest is linear: dst = base + lane*16.
  // Each wave stages its own 2KB quarter with 2 issues.
  auto stage = [&](int c, int b) {
    const ushort* gs = Sh + ((size_t)(split * 32 + c * 4)) * 1024 +
                       (size_t)w * 1024 + (size_t)l * 8;
    ushort* ls = &spanel[b][w * 1024];
    __builtin_amdgcn_global_load_lds(
        (const __attribute__((address_space(1))) void*)(const void*)gs,
        (__attribute__((address_space(3))) void*)(void*)ls, 16, 0, 0);
    __builtin_amdgcn_global_load_lds(
        (const __attribute__((address_space(1))) void*)(const void*)(gs + 512),
        (__attribute__((address_space(3))) void*)(void*)(ls + 512), 16, 0, 0);
    if (tid < 16)
      *(float4*)&ssq[b][tid * 4] =
          *(const float4*)&sqSc[sbase + c * 64 + tid * 4];
  };

  float bmr[4] = {-FLT_BIG, -FLT_BIG, -FLT_BIG, -FLT_BIG};

  stage(0, 0);
  __syncthreads();  // implicit vmcnt(0) drain: chunk 0 resident

  for (int c = 0; c < 8; ++c) {
    const int b = c & 1;
    if (c + 1 < 8) stage(c + 1, b ^ 1);  // async issue before compute

#pragma unroll
    for (int st = 0; st < 4; ++st) {
      const short8 h0 = *(const short8*)&spanel[b][st * 1024 + l * 8];
      const short8 h1 = *(const short8*)&spanel[b][st * 1024 + 512 + l * 8];
      const float4 sqv = *(const float4*)&ssq[b][st * 16 + lq * 4];
      float4v cinit;
      cinit[0] = sqv.x;
      cinit[1] = sqv.y;
      cinit[2] = sqv.z;
      cinit[3] = sqv.w;
#pragma unroll
      for (int t = 0; t < 4; ++t) {
        float4v a = MFMA16F(h0, qh[t][0], cinit);
        a = MFMA16F(h1, qh[t][1], a);
        // v_max3(a0,a1,a2) + max(a3,bmr) + max. Exact (assoc/comm).
        bmr[t] = fmaxf(fmaxf(fmaxf(a[0], a[1]), a[2]), fmaxf(a[3], bmr[t]));
      }
    }

    if ((((c + 1) * 4) & (BST - 1)) == 0) {  // finished a bmin block
      const int gb = split * (512 / SBLK) + ((c + 1) * 64 / SBLK) - 1;
#pragma unroll
      for (int t = 0; t < 4; ++t) {
        float v = bmr[t];
        v = fmaxf(v, __shfl_xor(v, 16, 64));
        v = fmaxf(v, __shfl_xor(v, 32, 64));
        if (lq == 0) bmin[(size_t)(qbase + t * 16 + lm) * NSB + gb] = -2.0f * v;
        bmr[t] = -FLT_BIG;
      }
    }
    __syncthreads();  // drains stage(c+1) + guards buffer reuse
  }
}

// ---------------------------------------------------------------------------
// Phase B (R21 verbatim, best measured): 4 queries per block, within-block
// work stealing + register-staged rescore. launch_bounds(256,3).
// Exact fp32 keys, row-ascending accumulation; strict-< ascending per lane
// + lexicographic merges => first-index.
template <int SBLK>
__global__ __launch_bounds__(256, 3) void k_phaseB(
    const float* __restrict__ S_T,   // [64][NTOT]
    const float* __restrict__ Q,     // [NTOT][64]
    const float* __restrict__ sqS, const float* __restrict__ sqQ,
    const float* __restrict__ bmin,
    const float* __restrict__ onehot, float* __restrict__ out) {
  constexpr int NSB = NTOT / SBLK;    // 128 or 64
  constexpr int NB64 = NSB / 64;
  constexpr int SPL = SBLK / 64;      // supports per lane: 2 or 4

  __shared__ float sQrow[4][64];
  __shared__ unsigned long long smask[4][NB64];
  __shared__ float sbk[4][4];
  __shared__ int sbi[4][4];

  const int lane = threadIdx.x & 63;
  const int w = threadIdx.x >> 6;
  const int q = blockIdx.x * 4 + w;

  if (lane < 16)
    *(float4*)&sQrow[w][lane * 4] = *(const float4*)&Q[(size_t)q * DIM + lane * 4];

  // Per-query certified filter width (no global data needed).
  const float eps = EPS_COEF * sqQ[q] + EPS_ABS;

  float bv[NB64];
#pragma unroll
  for (int j = 0; j < NB64; ++j) bv[j] = bmin[(size_t)q * NSB + j * 64 + lane];
  float m = bv[0];
#pragma unroll
  for (int j = 1; j < NB64; ++j) m = fminf(m, bv[j]);
#pragma unroll
  for (int d = 1; d < 64; d <<= 1) m = fminf(m, __shfl_xor(m, d, 64));
  const float thr = m + eps;

#pragma unroll
  for (int j = 0; j < NB64; ++j) {
    const unsigned long long msk = __ballot(bv[j] <= thr);
    if (lane == 0) smask[w][j] = msk;
  }
  __syncthreads();  // sQrow + smask visible block-wide

  // Round-robin the combined worklist. Items of a given query are visited
  // in ascending block order by every wave => per-lane ascending support
  // index => strict-< keeps the FIRST minimum.
  int idx = 0;
  for (int qq = 0; qq < 4; ++qq) {
    float bkq = FLT_BIG;
    int biq = 0;
    for (int j = 0; j < NB64; ++j) {
      unsigned long long msk = smask[qq][j];  // uniform broadcast read
      while (msk) {  // wave-uniform control
        const int b = j * 64 + (__ffsll((long long)msk) - 1);
        msk &= msk - 1;
        if ((idx++ & 3) != w) continue;
        const int s0 = b * SBLK + lane * SPL;
        if (SPL == 2) {
          // Register-staged: 2 halves x {32 float2 loads -> 64 fmaf}.
          float a0 = 0.f, a1 = 0.f;
#pragma unroll
          for (int h = 0; h < 2; ++h) {
            float2 x[32];
#pragma unroll
            for (int d = 0; d < 32; ++d)
              x[d] = *(const float2*)&S_T[(size_t)(h * 32 + d) * NTOT + s0];
#pragma unroll
            for (int d = 0; d < 32; ++d) {
              const float qd = sQrow[qq][h * 32 + d];
              a0 = fmaf(qd, x[d].x, a0);
              a1 = fmaf(qd, x[d].y, a1);
            }
          }
          const float2 sq2 = *(const float2*)&sqS[s0];
          const float k0 = fmaf(-2.f, a0, sq2.x);
          const float k1 = fmaf(-2.f, a1, sq2.y);
          bool u;  // ascending index, strict < => first minimum per lane
          u = k0 < bkq; bkq = u ? k0 : bkq; biq = u ? s0 : biq;
          u = k1 < bkq; bkq = u ? k1 : bkq; biq = u ? (s0 + 1) : biq;
        } else {
          // Register-staged: 4 quarters x {16 float4 loads -> 64 fmaf}.
          float a0 = 0.f, a1 = 0.f, a2 = 0.f, a3 = 0.f;
#pragma unroll
          for (int hh = 0; hh < 4; ++hh) {
            float4 x[16];
#pragma unroll
            for (int d = 0; d < 16; ++d)
              x[d] = *(const float4*)&S_T[(size_t)(hh * 16 + d) * NTOT + s0];
#pragma unroll
            for (int d = 0; d < 16; ++d) {
              const float qd = sQrow[qq][hh * 16 + d];
              a0 = fmaf(qd, x[d].x, a0);
              a1 = fmaf(qd, x[d].y, a1);
              a2 = fmaf(qd, x[d].z, a2);
              a3 = fmaf(qd, x[d].w, a3);
            }
          }
          const float4 sq4 = *(const float4*)&sqS[s0];
          const float k0 = fmaf(-2.f, a0, sq4.x);
          const float k1 = fmaf(-2.f, a1, sq4.y);
          const float k2 = fmaf(-2.f, a2, sq4.z);
          const float k3 = fmaf(-2.f, a3, sq4.w);
          bool u;
          u = k0 < bkq; bkq = u ? k0 : bkq; biq = u ? s0 : biq;
          u = k1 < bkq; bkq = u ? k1 : bkq; biq = u ? (s0 + 1) : biq;
          u = k2 < bkq; bkq = u ? k2 : bkq; biq = u ? (s0 + 2) : biq;
          u = k3 < bkq; bkq = u ? k3 : bkq; biq = u ? (s0 + 3) : biq;
        }
      }
    }
    // Cross-lane lexicographic argmin on exact keys => first-index.
#pragma unroll
    for (int d = 1; d < 64; d <<= 1) {
      const float ok = __shfl_xor(bkq, d, 64);
      const int oi = __shfl_xor(biq, d, 64);
      const bool u = (ok < bkq) || (ok == bkq && oi < biq);
      bkq = u ? ok : bkq;
      biq = u ? oi : biq;
    }
    if (lane == 0) { sbk[qq][w] = bkq; sbi[qq][w] = biq; }
  }
  __syncthreads();

  // Wave w: lexicographic merge of the 4 wave partials for query w.
  // (Disjoint block subsets; ties resolved by smaller index => first-index.)
  float fk = sbk[w][0];
  int fi = sbi[w][0];
#pragma unroll
  for (int ww = 1; ww < 4; ++ww) {
    const float ok = sbk[w][ww];
    const int oi = sbi[w][ww];
    const bool u = (ok < fk) || (ok == fk && oi < fi);
    fk = u ? ok : fk;
    fi = u ? oi : fi;
  }

  // Label: one-hot rows exact {0,1}; first 1 == np.argmax.
  const float ov = onehot[(size_t)fi * 64 + lane];
  const unsigned long long lmask = __ballot(ov > 0.5f);
  const int label = __ffsll((long long)lmask) - 1;
  out[(size_t)q * 64 + lane] = (lane == label) ? 1.0f : 0.0f;
}

// ---------------------------------------------------------------------------
extern "C" void kernel_launch(void* const* d_in, const int* in_sizes, int n_in,
                              void* d_out, int out_size, void* d_ws, size_t ws_size,
                              hipStream_t stream) {
  const float* S = (const float*)d_in[0];   // [16384][64]
  const float* Q = (const float*)d_in[1];   // [16384][64]
  const float* OH = (const float*)d_in[2];  // [16384][64]
  float* out = (float*)d_out;

  char* ws = (char*)d_ws;
  ushort* Sh = (ushort*)ws;                                  // [0, 2MB)
  ushort* Qh = (ushort*)(ws + (2u << 20));                   // [2, 4MB)
  float* S_T = (float*)(ws + (4u << 20));                    // [4, 8MB)
  float* sqS = (float*)(ws + (8u << 20));                    // 64 KB
  float* sqQ = (float*)(ws + (8u << 20) + (64u << 10));      // 64 KB
  float* sqSc = (float*)(ws + (8u << 20) + (128u << 10));    // 64 KB
  float* bmin = (float*)(ws + (8u << 20) + (192u << 10));    // up to 8 MB

  k_prep<<<dim3(512), 256, 0, stream>>>(S, Q, Sh, Qh, sqS, sqQ, sqSc, S_T);

  // 128-granular bmin (8 MB) if workspace allows (proven >=20 MB in R14);
  // else 256-granular (4 MB). Need: 8.19 + 8 = 16.19 MB / 12.19 MB.
  if (ws_size >= (17u << 20)) {
    k_phaseA<8><<<dim3(32, NTOT / 256), 256, 0, stream>>>(Sh, Qh, sqSc, bmin);
    k_phaseB<128><<<dim3(NTOT / 4), 256, 0, stream>>>(S_T, Q, sqS, sqQ,
                                                      bmin, OH, out);
  } else {
    k_phaseA<16><<<dim3(32, NTOT / 256), 256, 0, stream>>>(Sh, Qh, sqSc, bmin);
    k_phaseB<256><<<dim3(NTOT / 4), 256, 0, stream>>>(S_T, Q, sqS, sqQ,
                                                      bmin, OH, out);
  }
  (void)in_sizes; (void)n_in; (void)out_size; (void)ws_size;
}